// Round 5
// baseline (91.722 us; speedup 1.0000x reference)
//
#include <hip/hip_runtime.h>

// SpanNERDecoder: B=4, S=512, D=768, L=10, E=25, C=9, N=5075 spans.
// scores[b,n,c] = max_{p in [st,en)} we[b,p,:] . W[:D,c] + (len_embed[len] . W[D:,c] + b[c])
//
// ROUND 5 = DIAGNOSTIC: identical kernel to round 4, launched TWICE per
// kernel_launch (deterministic, writes same values twice — graph-safe).
// dur_us delta vs round 4 (79.56) isolates the kernel's true duration,
// which the top-5 profile cutoff (~40 us poison fills) hides.

#define SS 512
#define DD 768
#define LL 10
#define EE 25
#define CC 9
#define NSPANS 5075

__device__ __forceinline__ float wave_sum64(float v) {
    int x;
    // quad_perm [1,0,3,2] == xor1
    x = __builtin_amdgcn_update_dpp(0, __float_as_int(v), 0xB1, 0xF, 0xF, true);
    v += __int_as_float(x);
    // quad_perm [2,3,0,1] == xor2
    x = __builtin_amdgcn_update_dpp(0, __float_as_int(v), 0x4E, 0xF, 0xF, true);
    v += __int_as_float(x);
    // row_half_mirror == xor7 (acts as xor4: values already quad-uniform)
    x = __builtin_amdgcn_update_dpp(0, __float_as_int(v), 0x141, 0xF, 0xF, true);
    v += __int_as_float(x);
    // row_mirror == xor15 (acts as xor8: values already 8-uniform)
    x = __builtin_amdgcn_update_dpp(0, __float_as_int(v), 0x140, 0xF, 0xF, true);
    v += __int_as_float(x);
    v += __shfl_xor(v, 16, 64);
    v += __shfl_xor(v, 32, 64);
    return v;
}

__global__ __launch_bounds__(256, 2) void spanner_kernel(
    const float* __restrict__ we,    // [B,S,D]
    const float* __restrict__ lene,  // [L,E]
    const float* __restrict__ W,     // [D+E, C]
    const float* __restrict__ bias,  // [C]
    float* __restrict__ out)         // [B,N,C]
{
    __shared__ float lenW[LL][CC];
    const int t = threadIdx.x;

    // Fold len_embed @ W[D:,:] + bias into a 10x9 table (once per block).
    if (t < LL * CC) {
        const int l = t / CC, c = t % CC;
        float s = bias[c];
#pragma unroll
        for (int e = 0; e < EE; ++e)
            s += lene[l * EE + e] * W[(DD + e) * CC + c];
        lenW[l][c] = s;
    }
    __syncthreads();

    const int lane = t & 63;
    const int gid  = blockIdx.x * 4 + (t >> 6);   // 0..2047 == B*S
    const int b    = gid >> 9;
    const int i    = gid & (SS - 1);
    const int cnt  = min(LL, SS - i);
    const int base = (i <= SS - LL) ? i * LL
                     : (NSPANS - ((SS - i) * (SS - i + 1)) / 2);

    // W fragment: lane owns dims d = c0*256 + lane*4 + q. 36 contiguous floats
    // per c0 -> 9 float4 loads each.
    float Wr[3][4][CC];
#pragma unroll
    for (int c0 = 0; c0 < 3; ++c0) {
        const float4* wp = reinterpret_cast<const float4*>(W + (c0 * 256 + lane * 4) * CC);
        float4 wv[9];
#pragma unroll
        for (int j = 0; j < 9; ++j) wv[j] = wp[j];
        const float* wf = reinterpret_cast<const float*>(wv);
#pragma unroll
        for (int q = 0; q < 4; ++q)
#pragma unroll
            for (int c = 0; c < CC; ++c)
                Wr[c0][q][c] = wf[q * CC + c];
    }

    const float4* rowbase = reinterpret_cast<const float4*>(we) + (size_t)(b * SS) * (DD / 4);

    float4 r0 = rowbase[(size_t)i * (DD / 4) + lane];
    float4 r1 = rowbase[(size_t)i * (DD / 4) + 64 + lane];
    float4 r2 = rowbase[(size_t)i * (DD / 4) + 128 + lane];

    float m[3][4];
#pragma unroll
    for (int c0 = 0; c0 < 3; ++c0)
#pragma unroll
        for (int q = 0; q < 4; ++q) m[c0][q] = -INFINITY;

    float acc[5][CC];
    float res[LL];

#pragma unroll
    for (int k = 0; k < LL; ++k) {
        // Fold current row into the running max.
        {
            const float* f;
            f = (const float*)&r0;
#pragma unroll
            for (int q = 0; q < 4; ++q) m[0][q] = fmaxf(m[0][q], f[q]);
            f = (const float*)&r1;
#pragma unroll
            for (int q = 0; q < 4; ++q) m[1][q] = fmaxf(m[1][q], f[q]);
            f = (const float*)&r2;
#pragma unroll
            for (int q = 0; q < 4; ++q) m[2][q] = fmaxf(m[2][q], f[q]);
        }

        // Prefetch next row (clamped; spans past cnt are never stored).
        if (k + 1 < LL) {
            const int nr = min(i + k + 1, SS - 1);
            r0 = rowbase[(size_t)nr * (DD / 4) + lane];
            r1 = rowbase[(size_t)nr * (DD / 4) + 64 + lane];
            r2 = rowbase[(size_t)nr * (DD / 4) + 128 + lane];
        }

        // Per-lane partial dot: 12 dims x 9 classes.
        const int kk = k % 5;
#pragma unroll
        for (int c = 0; c < CC; ++c) acc[kk][c] = 0.0f;
#pragma unroll
        for (int c0 = 0; c0 < 3; ++c0)
#pragma unroll
            for (int q = 0; q < 4; ++q)
#pragma unroll
                for (int c = 0; c < CC; ++c)
                    acc[kk][c] = fmaf(m[c0][q], Wr[c0][q][c], acc[kk][c]);

        // Batched reduction every 5 spans: 45 independent chains.
        if (kk == 4) {
#pragma unroll
            for (int kb = 0; kb < 5; ++kb) {
                float s[CC];
#pragma unroll
                for (int c = 0; c < CC; ++c) s[c] = wave_sum64(acc[kb][c]);
                float v = s[0];
#pragma unroll
                for (int c = 1; c < CC; ++c) v = (lane == c) ? s[c] : v;
                res[k - 4 + kb] = v;
            }
        }
    }

    float* const outb = out + ((size_t)b * NSPANS + base) * CC;
    if (lane < CC) {
#pragma unroll
        for (int k = 0; k < LL; ++k)
            if (k < cnt) outb[k * CC + lane] = res[k] + lenW[k][lane];
    }
}

extern "C" void kernel_launch(void* const* d_in, const int* in_sizes, int n_in,
                              void* d_out, int out_size, void* d_ws, size_t ws_size,
                              hipStream_t stream) {
    const float* we   = (const float*)d_in[0];
    const float* lene = (const float*)d_in[1];
    const float* W    = (const float*)d_in[2];
    const float* bias = (const float*)d_in[3];
    float* out        = (float*)d_out;

    // DIAGNOSTIC double-launch: dur_us = harness_floor + 2 * kernel_time.
    // Subtracting round-4's dur_us (harness_floor + 1x) isolates kernel_time.
    spanner_kernel<<<512, 256, 0, stream>>>(we, lene, W, bias, out);
    spanner_kernel<<<512, 256, 0, stream>>>(we, lene, W, bias, out);
}

// Round 7
// 81.331 us; speedup vs baseline: 1.1278x; 1.1278x over previous
//
#include <hip/hip_runtime.h>

// SpanNERDecoder: B=4, S=512, D=768, L=10, E=25, C=9, N=5075 spans.
// scores[b,n,c] = max_{p in [st,en)} we[b,p,:] . W[:D,c] + (len_embed[len] . W[D:,c] + b[c])
//
// ROUND 7 (= round-6 kernel, re-bench after GPU timeout):
// one 192-thread block per (b,i); 4 dims/thread (float4 rows, Wr=36 regs).
// Diagnosed round 5: kernel ~12.2us, latency-bound at 2 waves/SIMD (VGPR>128).
// This cuts VGPR to ~80 (4+ waves/SIMD), shortens per-wave critical path ~2x,
// and replaces DS-heavy butterflies with 4 DPP steps + one LDS combine phase.

#define SS 512
#define DD 768
#define LL 10
#define EE 25
#define CC 9
#define NSPANS 5075
#define TPB 192   // 768 dims / 4 per thread

__device__ __forceinline__ float dpp_reduce16(float v) {
    // Butterfly over masks 1,2,4,8 -> every 16-lane group holds its partial sum.
    int x;
    x = __builtin_amdgcn_update_dpp(0, __float_as_int(v), 0xB1, 0xF, 0xF, true);   // quad_perm xor1
    v += __int_as_float(x);
    x = __builtin_amdgcn_update_dpp(0, __float_as_int(v), 0x4E, 0xF, 0xF, true);   // quad_perm xor2
    v += __int_as_float(x);
    x = __builtin_amdgcn_update_dpp(0, __float_as_int(v), 0x141, 0xF, 0xF, true);  // row_half_mirror (xor4 on quad-uniform)
    v += __int_as_float(x);
    x = __builtin_amdgcn_update_dpp(0, __float_as_int(v), 0x140, 0xF, 0xF, true);  // row_mirror (xor8 on 8-uniform)
    v += __int_as_float(x);
    return v;
}

__global__ __launch_bounds__(TPB, 4) void spanner_kernel(
    const float* __restrict__ we,    // [B,S,D]
    const float* __restrict__ lene,  // [L,E]
    const float* __restrict__ W,     // [D+E, C]
    const float* __restrict__ bias,  // [C]
    float* __restrict__ out)         // [B,N,C]
{
    // [span][class][wave][group16] so the 12 partials per (span,class) are contiguous.
    __shared__ __align__(16) float sp[LL][CC][3][4];
    __shared__ float lenW[LL][CC];

    const int t    = threadIdx.x;
    const int lane = t & 63;
    const int wvid = t >> 6;          // 0..2
    const int gid  = blockIdx.x;      // 0..2047 == B*S
    const int b    = gid >> 9;
    const int i    = gid & (SS - 1);
    const int cnt  = min(LL, SS - i);
    const int base = (i <= SS - LL) ? i * LL
                     : (NSPANS - ((SS - i) * (SS - i + 1)) / 2);

    // Fold len_embed @ W[D:,:] + bias into 10x9 table (threads 0..89).
    if (t < LL * CC) {
        const int l = t / CC, c = t % CC;
        float s = bias[c];
#pragma unroll
        for (int e = 0; e < EE; ++e)
            s += lene[l * EE + e] * W[(DD + e) * CC + c];
        lenW[l][c] = s;
    }

    // W fragment: thread owns dims d = t*4+q -> 36 consecutive floats, 16B-aligned.
    float Wr[4][CC];
    {
        const float4* wp = reinterpret_cast<const float4*>(W) + t * 9;
        float4 wv4[9];
#pragma unroll
        for (int j = 0; j < 9; ++j) wv4[j] = wp[j];
        const float* wf = reinterpret_cast<const float*>(wv4);
#pragma unroll
        for (int q = 0; q < 4; ++q)
#pragma unroll
            for (int c = 0; c < CC; ++c)
                Wr[q][c] = wf[q * CC + c];
    }

    const float* rowb = we + ((size_t)b * SS) * DD + t * 4;
    float4 r = *reinterpret_cast<const float4*>(rowb + (size_t)i * DD);

    float m[4] = {-INFINITY, -INFINITY, -INFINITY, -INFINITY};

    const int cs  = lane & 15;   // class slot for writer lanes
    const int grp = lane >> 4;   // 16-lane group id

#pragma unroll
    for (int s = 0; s < LL; ++s) {
        // Fold current row into running max.
        m[0] = fmaxf(m[0], r.x);
        m[1] = fmaxf(m[1], r.y);
        m[2] = fmaxf(m[2], r.z);
        m[3] = fmaxf(m[3], r.w);

        // Prefetch next row (clamped; spans past cnt are never stored).
        if (s + 1 < LL) {
            const int nr = min(i + s + 1, SS - 1);
            r = *reinterpret_cast<const float4*>(rowb + (size_t)nr * DD);
        }

        // Per-thread partial dot: 4 dims x 9 classes.
        float acc[CC];
#pragma unroll
        for (int c = 0; c < CC; ++c) acc[c] = 0.0f;
#pragma unroll
        for (int q = 0; q < 4; ++q)
#pragma unroll
            for (int c = 0; c < CC; ++c)
                acc[c] = fmaf(m[q], Wr[q][c], acc[c]);

        // Reduce to 16-lane-group partials (DPP only, no DS).
#pragma unroll
        for (int c = 0; c < CC; ++c) acc[c] = dpp_reduce16(acc[c]);

        // Writer lane g*16+c stores class c's partial for group g (static select).
        float v = acc[0];
#pragma unroll
        for (int c = 1; c < CC; ++c) v = (cs == c) ? acc[c] : v;
        if (cs < CC) sp[s][cs][wvid][grp] = v;
    }

    __syncthreads();

    // Final combine: thread j<90 sums the 12 partials (3 float4) for (span,class).
    if (t < LL * CC) {
        const int s = t / CC, c = t % CC;
        const float4* pp = reinterpret_cast<const float4*>(&sp[s][c][0][0]);
        const float4 p0 = pp[0], p1 = pp[1], p2 = pp[2];
        const float sum = ((p0.x + p0.y) + (p0.z + p0.w))
                        + ((p1.x + p1.y) + (p1.z + p1.w))
                        + ((p2.x + p2.y) + (p2.z + p2.w));
        if (s < cnt)
            out[((size_t)b * NSPANS + base + s) * CC + c] = sum + lenW[s][c];
    }
}

extern "C" void kernel_launch(void* const* d_in, const int* in_sizes, int n_in,
                              void* d_out, int out_size, void* d_ws, size_t ws_size,
                              hipStream_t stream) {
    const float* we   = (const float*)d_in[0];
    const float* lene = (const float*)d_in[1];
    const float* W    = (const float*)d_in[2];
    const float* bias = (const float*)d_in[3];
    float* out        = (float*)d_out;

    // One block per (b, start): 2048 blocks x 192 threads.
    spanner_kernel<<<2048, TPB, 0, stream>>>(we, lene, W, bias, out);
}